// Round 1
// baseline (40.362 us; speedup 1.0000x reference)
//
#include <hip/hip_runtime.h>

// Problem constants (from reference): x [4,64,256,256] f32, w [4,8,9,256,256] f32
// out [4,64,256,256] f32. groups=8, group_in=8, group_out=8, ks=3, pad=1.
#define NB 4
#define IC 64
#define HH 256
#define WW 256
#define GROUPS 8
#define GROUP_IN 8
#define GROUP_OUT 8

constexpr int HW = HH * WW;              // 65536
constexpr int PLANES = NB * GROUPS;      // 32
constexpr int VEC4_PER_PLANE = HW / 4;   // 16384
constexpr int TOTAL_VEC4 = PLANES * VEC4_PER_PLANE; // 524288

// ---------------------------------------------------------------------------
// K1: xs[n,g,:,:] = sum over 8 input channels of group g.
// One thread = 4 pixels (float4). 8 coalesced float4 loads, 1 float4 store.
// ---------------------------------------------------------------------------
__global__ __launch_bounds__(256) void ska_group_sum(const float* __restrict__ x,
                                                     float* __restrict__ xs) {
    int gid = blockIdx.x * 256 + threadIdx.x;
    if (gid >= TOTAL_VEC4) return;
    int plane  = gid >> 14;          // / 16384  -> n*8+g
    int within = gid & 16383;
    const float4* xp = reinterpret_cast<const float4*>(x)
                     + (size_t)plane * GROUP_IN * VEC4_PER_PLANE + within;
    float4 acc = xp[0];
#pragma unroll
    for (int c = 1; c < GROUP_IN; ++c) {
        float4 v = xp[(size_t)c * VEC4_PER_PLANE];
        acc.x += v.x; acc.y += v.y; acc.z += v.z; acc.w += v.w;
    }
    reinterpret_cast<float4*>(xs)[(size_t)plane * VEC4_PER_PLANE + within] = acc;
}

// ---------------------------------------------------------------------------
// K2: og[n,g,y,x] = sum_{kh,kw} w[n,g,kh*3+kw,y,x] * xs_pad[n,g,y+kh-1,x+kw-1]
//     out[n, g*8+j, y, x] = og  for j in 0..7
// One thread = 4 pixels along x. Zero-padded borders.
// ---------------------------------------------------------------------------
__global__ __launch_bounds__(256) void ska_conv(const float* __restrict__ wgt,
                                                const float* __restrict__ xs,
                                                float* __restrict__ out) {
    int gid = blockIdx.x * 256 + threadIdx.x;
    if (gid >= TOTAL_VEC4) return;
    int plane  = gid >> 14;          // n*8+g
    int within = gid & 16383;
    int y  = within >> 6;            // / (WW/4)
    int x0 = (within & 63) << 2;

    const float* xsp = xs + (size_t)plane * HW;

    // e[r][0] = left halo, e[r][1..4] = 4 center pixels, e[r][5] = right halo
    float e[3][6];
#pragma unroll
    for (int r = 0; r < 3; ++r) {
        int yy = y + r - 1;
        if (yy < 0 || yy >= HH) {
#pragma unroll
            for (int j = 0; j < 6; ++j) e[r][j] = 0.f;
        } else {
            const float* rp = xsp + (size_t)yy * WW;
            float4 v = *reinterpret_cast<const float4*>(rp + x0);
            e[r][1] = v.x; e[r][2] = v.y; e[r][3] = v.z; e[r][4] = v.w;
            e[r][0] = (x0 > 0)       ? rp[x0 - 1] : 0.f;
            e[r][5] = (x0 + 4 < WW)  ? rp[x0 + 4] : 0.f;
        }
    }

    const float* wbase = wgt + (size_t)plane * 9 * HW + (size_t)y * WW + x0;
    float4 acc = {0.f, 0.f, 0.f, 0.f};
#pragma unroll
    for (int kh = 0; kh < 3; ++kh) {
#pragma unroll
        for (int kw = 0; kw < 3; ++kw) {
            float4 wv = *reinterpret_cast<const float4*>(wbase + (size_t)(kh * 3 + kw) * HW);
            acc.x += wv.x * e[kh][kw + 0];
            acc.y += wv.y * e[kh][kw + 1];
            acc.z += wv.z * e[kh][kw + 2];
            acc.w += wv.w * e[kh][kw + 3];
        }
    }

    int n = plane >> 3;
    int g = plane & 7;
    float4* ob = reinterpret_cast<float4*>(out)
               + ((size_t)(n * IC + g * GROUP_OUT) * VEC4_PER_PLANE)
               + ((size_t)y * WW + x0) / 4;
#pragma unroll
    for (int j = 0; j < GROUP_OUT; ++j) ob[(size_t)j * VEC4_PER_PLANE] = acc;
}

extern "C" void kernel_launch(void* const* d_in, const int* in_sizes, int n_in,
                              void* d_out, int out_size, void* d_ws, size_t ws_size,
                              hipStream_t stream) {
    const float* x   = (const float*)d_in[0];
    const float* wgt = (const float*)d_in[1];
    float* out = (float*)d_out;
    float* xs  = (float*)d_ws;   // needs PLANES*HW*4 = 8 MiB

    constexpr int THREADS = 256;
    constexpr int BLOCKS  = (TOTAL_VEC4 + THREADS - 1) / THREADS; // 2048

    ska_group_sum<<<BLOCKS, THREADS, 0, stream>>>(x, xs);
    ska_conv<<<BLOCKS, THREADS, 0, stream>>>(wgt, xs, out);
}

// Round 2
// 36.405 us; speedup vs baseline: 1.1087x; 1.1087x over previous
//
#include <hip/hip_runtime.h>

// x [4,64,256,256] f32, w [4,8,9,256,256] f32, out [4,64,256,256] f32
// groups=8, group_in=8, group_out=8, ks=3, pad=1.
#define NB 4
#define ICC 64
#define HH 256
#define WW 256
#define GROUP_IN 8
#define GROUP_OUT 8
#define TROWS 16
#define HALO_ROWS (TROWS + 2)

constexpr int HW = HH * WW;                  // 65536
constexpr int PLANES = NB * 8;               // 32  (n*8+g)
constexpr int TILES_PER_PLANE = HH / TROWS;  // 16
constexpr int W4 = WW / 4;                   // 64
constexpr int THREADS = 512;

// One block = one (plane, 16-row tile).
// Phase 1: group channel-sum of 18 halo rows -> LDS (re-reads 2/18 of x as halo).
// Phase 2: 3x3 per-pixel stencil with w, broadcast-store to 8 output channels.
__global__ __launch_bounds__(THREADS) void ska_fused(const float* __restrict__ x,
                                                     const float* __restrict__ wgt,
                                                     float* __restrict__ out) {
    __shared__ float xs[HALO_ROWS][WW];

    const int bid   = blockIdx.x;
    const int plane = bid >> 4;        // / TILES_PER_PLANE
    const int tile  = bid & 15;
    const int y0    = tile * TROWS;
    const int tid   = threadIdx.x;

    // ---- Phase 1: xs[r][:] = sum_c x[plane*8+c][y0-1+r][:]
    const float4* xbase = reinterpret_cast<const float4*>(x)
                        + (size_t)plane * GROUP_IN * (HW / 4);
    for (int idx = tid; idx < HALO_ROWS * W4; idx += THREADS) {
        const int r  = idx >> 6;       // / W4
        const int c4 = idx & 63;
        const int yy = y0 - 1 + r;
        float4 acc = {0.f, 0.f, 0.f, 0.f};
        if (yy >= 0 && yy < HH) {
            const float4* p = xbase + (size_t)yy * W4 + c4;
#pragma unroll
            for (int c = 0; c < GROUP_IN; ++c) {
                float4 v = p[(size_t)c * (HW / 4)];
                acc.x += v.x; acc.y += v.y; acc.z += v.z; acc.w += v.w;
            }
        }
        *reinterpret_cast<float4*>(&xs[r][c4 * 4]) = acc;
    }
    __syncthreads();

    // ---- Phase 2: stencil + broadcast store
    const int c4    = tid & 63;
    const int x0    = c4 * 4;
    const int rbase = tid >> 6;        // 0..7 (one row per wave)
    const float* wplane = wgt + (size_t)plane * 9 * HW;
    const int n = plane >> 3, g = plane & 7;
    float4* outbase = reinterpret_cast<float4*>(out)
                    + (size_t)(n * ICC + g * GROUP_OUT) * (HW / 4);

#pragma unroll
    for (int s = 0; s < 2; ++s) {
        const int lr = s * 8 + rbase;  // local row 0..15; xs row lr..lr+2 = y-1..y+1
        const int y  = y0 + lr;

        float e[3][6];
#pragma unroll
        for (int r = 0; r < 3; ++r) {
            const float* rp = &xs[lr + r][0];
            float4 v = *reinterpret_cast<const float4*>(rp + x0);
            e[r][1] = v.x; e[r][2] = v.y; e[r][3] = v.z; e[r][4] = v.w;
            e[r][0] = (x0 > 0)      ? rp[x0 - 1] : 0.f;
            e[r][5] = (x0 + 4 < WW) ? rp[x0 + 4] : 0.f;
        }

        const float* wb = wplane + (size_t)y * WW + x0;
        float4 acc = {0.f, 0.f, 0.f, 0.f};
#pragma unroll
        for (int kh = 0; kh < 3; ++kh)
#pragma unroll
            for (int kw = 0; kw < 3; ++kw) {
                float4 wv = *reinterpret_cast<const float4*>(wb + (size_t)(kh * 3 + kw) * HW);
                acc.x += wv.x * e[kh][kw + 0];
                acc.y += wv.y * e[kh][kw + 1];
                acc.z += wv.z * e[kh][kw + 2];
                acc.w += wv.w * e[kh][kw + 3];
            }

        float4* ob = outbase + ((size_t)y * WW + x0) / 4;
#pragma unroll
        for (int j = 0; j < GROUP_OUT; ++j) ob[(size_t)j * (HW / 4)] = acc;
    }
}

extern "C" void kernel_launch(void* const* d_in, const int* in_sizes, int n_in,
                              void* d_out, int out_size, void* d_ws, size_t ws_size,
                              hipStream_t stream) {
    const float* x   = (const float*)d_in[0];
    const float* wgt = (const float*)d_in[1];
    float* out = (float*)d_out;

    constexpr int BLOCKS = PLANES * TILES_PER_PLANE;  // 512
    ska_fused<<<BLOCKS, THREADS, 0, stream>>>(x, wgt, out);
}

// Round 3
// 36.095 us; speedup vs baseline: 1.1182x; 1.0086x over previous
//
#include <hip/hip_runtime.h>

// x [4,64,256,256] f32, w [4,8,9,256,256] f32, out [4,64,256,256] f32
// groups=8, group_in=8, group_out=8, ks=3, pad=1.
#define NB 4
#define ICC 64
#define HH 256
#define WW 256
#define GROUP_IN 8
#define GROUP_OUT 8
#define TROWS 16
#define HALO_ROWS (TROWS + 2)

constexpr int HW = HH * WW;                  // 65536
constexpr int PLANES = NB * 8;               // 32  (n*8+g)
constexpr int TILES_PER_PLANE = HH / TROWS;  // 16
constexpr int W4 = WW / 4;                   // 64
constexpr int THREADS = 1024;                // 16 waves; 2 blocks/CU = full 32 waves/CU

// One block = one (plane, 16-row tile).
// Phase 1: group channel-sum of 18 halo rows -> LDS (12.5% x halo re-read).
// Phase 2: each thread owns one (row, 4-pixel) site; horizontal halo via shfl
//          (a wave's 64 lanes are exactly one 256-px row); broadcast-store x8.
__global__ __launch_bounds__(THREADS) void ska_fused(const float* __restrict__ x,
                                                     const float* __restrict__ wgt,
                                                     float* __restrict__ out) {
    __shared__ float xs[HALO_ROWS][WW];

    const int bid   = blockIdx.x;
    const int plane = bid >> 4;        // / TILES_PER_PLANE
    const int tile  = bid & 15;
    const int y0    = tile * TROWS;
    const int tid   = threadIdx.x;

    // ---- Phase 1: xs[r][:] = sum_c x[plane*8+c][y0-1+r][:]
    const float4* xbase = reinterpret_cast<const float4*>(x)
                        + (size_t)plane * GROUP_IN * (HW / 4);
    for (int idx = tid; idx < HALO_ROWS * W4; idx += THREADS) {
        const int r  = idx >> 6;       // / W4
        const int c4 = idx & 63;
        const int yy = y0 - 1 + r;
        float4 acc = {0.f, 0.f, 0.f, 0.f};
        if (yy >= 0 && yy < HH) {
            const float4* p = xbase + (size_t)yy * W4 + c4;
#pragma unroll
            for (int c = 0; c < GROUP_IN; ++c) {
                float4 v = p[(size_t)c * (HW / 4)];
                acc.x += v.x; acc.y += v.y; acc.z += v.z; acc.w += v.w;
            }
        }
        *reinterpret_cast<float4*>(&xs[r][c4 * 4]) = acc;
    }
    __syncthreads();

    // ---- Phase 2: stencil + broadcast store
    const int lane = tid & 63;         // == c4; wave == one image row
    const int x0   = lane << 2;
    const int lr   = tid >> 6;         // local row 0..15
    const int y    = y0 + lr;

    // e[r][0] = left halo, e[r][1..4] = center, e[r][5] = right halo
    float e[3][6];
#pragma unroll
    for (int r = 0; r < 3; ++r) {
        float4 v = *reinterpret_cast<const float4*>(&xs[lr + r][x0]);
        e[r][1] = v.x; e[r][2] = v.y; e[r][3] = v.z; e[r][4] = v.w;
        float left  = __shfl_up(v.w, 1);
        float right = __shfl_down(v.x, 1);
        e[r][0] = (lane == 0)  ? 0.f : left;    // image-left zero pad
        e[r][5] = (lane == 63) ? 0.f : right;   // image-right zero pad
    }

    const float* wb = wgt + (size_t)plane * 9 * HW + (size_t)y * WW + x0;
    float4 acc = {0.f, 0.f, 0.f, 0.f};
#pragma unroll
    for (int kh = 0; kh < 3; ++kh)
#pragma unroll
        for (int kw = 0; kw < 3; ++kw) {
            float4 wv = *reinterpret_cast<const float4*>(wb + (size_t)(kh * 3 + kw) * HW);
            acc.x += wv.x * e[kh][kw + 0];
            acc.y += wv.y * e[kh][kw + 1];
            acc.z += wv.z * e[kh][kw + 2];
            acc.w += wv.w * e[kh][kw + 3];
        }

    const int n = plane >> 3, g = plane & 7;
    float4* ob = reinterpret_cast<float4*>(out)
               + (size_t)(n * ICC + g * GROUP_OUT) * (HW / 4)
               + ((size_t)y * WW + x0) / 4;
#pragma unroll
    for (int j = 0; j < GROUP_OUT; ++j) ob[(size_t)j * (HW / 4)] = acc;
}

extern "C" void kernel_launch(void* const* d_in, const int* in_sizes, int n_in,
                              void* d_out, int out_size, void* d_ws, size_t ws_size,
                              hipStream_t stream) {
    const float* x   = (const float*)d_in[0];
    const float* wgt = (const float*)d_in[1];
    float* out = (float*)d_out;

    constexpr int BLOCKS = PLANES * TILES_PER_PLANE;  // 512
    ska_fused<<<BLOCKS, THREADS, 0, stream>>>(x, wgt, out);
}